// Round 1
// baseline (417.249 us; speedup 1.0000x reference)
//
#include <hip/hip_runtime.h>
#include <hip/hip_bf16.h>

#define B_ 4
#define N_ 4096
#define D_ 128

typedef __bf16 bf16x8 __attribute__((ext_vector_type(8)));
typedef __bf16 bf16x4 __attribute__((ext_vector_type(4)));
typedef float f32x4 __attribute__((ext_vector_type(4)));

// alpha = log2(e) / sqrt(128): scores scaled to base-2 domain
#define ALPHA 0.12752361680972262f

// ws layout:
//   Qb  : bf16 [B][N][D]   @ 0        (4 MiB)
//   Kb  : bf16 [B][N][D]   @ 4 MiB
//   Vt  : bf16 [B][D][N]   @ 8 MiB    (transposed V)
//   linv: f32  [B][N]      @ 12 MiB   (1 / column-sum of exp2)

// ---------------------------------------------------------------------------
// Kernel A: convert Q,K -> bf16; convert+transpose V -> Vt
// blocks [0,4096): Q/K convert, 4 floats/thread
// blocks [4096,6144): V transpose, 4 keys/thread (gather reads, coalesced writes)
// ---------------------------------------------------------------------------
__global__ __launch_bounds__(256) void cvt_kernel(
    const float* __restrict__ q, const float* __restrict__ k,
    const float* __restrict__ v,
    __bf16* __restrict__ qb, __bf16* __restrict__ kb, __bf16* __restrict__ vt)
{
    int bid = blockIdx.x;
    int tid = threadIdx.x;
    if (bid < 4096) {
        int i4 = bid * 256 + tid;                 // 0 .. 1,048,575
        const float4* src;
        __bf16* dst;
        int off;
        if (i4 < (B_ * N_ * D_ / 4)) { src = (const float4*)q; dst = qb; off = i4; }
        else { src = (const float4*)k; dst = kb; off = i4 - B_ * N_ * D_ / 4; }
        float4 x = src[off];
        bf16x4 y;
        y[0] = (__bf16)x.x; y[1] = (__bf16)x.y; y[2] = (__bf16)x.z; y[3] = (__bf16)x.w;
        *(bf16x4*)(dst + (size_t)off * 4) = y;
    } else {
        int g = (bid - 4096) * 256 + tid;         // 0 .. 524,287
        int kg = g & 1023;                        // key group (4 keys each)
        int rest = g >> 10;
        int d = rest & 127;
        int b = rest >> 7;
        const float* vp = v + ((size_t)b * N_ + (size_t)kg * 4) * D_ + d;
        bf16x4 y;
        y[0] = (__bf16)vp[0];
        y[1] = (__bf16)vp[D_];
        y[2] = (__bf16)vp[2 * D_];
        y[3] = (__bf16)vp[3 * D_];
        *(bf16x4*)(vt + ((size_t)b * D_ + d) * N_ + (size_t)kg * 4) = y;
    }
}

// ---------------------------------------------------------------------------
// Kernel B: column stats. l[k] = sum_q 2^(alpha * dot(q_row, k_row)); store 1/l.
// grid = B * N/64 blocks of 256 (4 waves); each wave owns 16 keys (A = K),
// loops all q in tiles of 64 (B = Q^T). S^T C-layout: lane holds 4 key-rows
// (quad*4+r) x 1 q-col (lane&15). Accumulate exp2 per lane, shfl-reduce over
// the 16 q-columns at the end.
// ---------------------------------------------------------------------------
__global__ __launch_bounds__(256) void stats_kernel(
    const __bf16* __restrict__ qb, const __bf16* __restrict__ kb,
    float* __restrict__ linv)
{
    int b = blockIdx.x >> 6;
    int key_base = (blockIdx.x & 63) * 64;
    int w = threadIdx.x >> 6;
    int L = threadIdx.x & 63;
    int quad = L >> 4, l15 = L & 15;

    const bf16x8* kv = (const bf16x8*)(kb + ((size_t)b * N_) * D_);
    const bf16x8* qv = (const bf16x8*)(qb + ((size_t)b * N_) * D_);

    int arow = key_base + w * 16 + l15;
    bf16x8 af[4];
#pragma unroll
    for (int f = 0; f < 4; ++f) af[f] = kv[arow * 16 + f * 4 + quad];

    float lp0 = 0.f, lp1 = 0.f, lp2 = 0.f, lp3 = 0.f;
    for (int qt = 0; qt < N_; qt += 64) {
        bf16x8 bq[4][4];
#pragma unroll
        for (int s = 0; s < 4; ++s)
#pragma unroll
            for (int f = 0; f < 4; ++f)
                bq[s][f] = qv[(qt + s * 16 + l15) * 16 + f * 4 + quad];
#pragma unroll
        for (int s = 0; s < 4; ++s) {
            f32x4 acc = {0.f, 0.f, 0.f, 0.f};
#pragma unroll
            for (int f = 0; f < 4; ++f)
                acc = __builtin_amdgcn_mfma_f32_16x16x32_bf16(af[f], bq[s][f], acc, 0, 0, 0);
            lp0 += __builtin_amdgcn_exp2f(acc[0] * ALPHA);
            lp1 += __builtin_amdgcn_exp2f(acc[1] * ALPHA);
            lp2 += __builtin_amdgcn_exp2f(acc[2] * ALPHA);
            lp3 += __builtin_amdgcn_exp2f(acc[3] * ALPHA);
        }
    }
    // reduce over the 16 q-columns (lanes sharing a quad)
#pragma unroll
    for (int m = 1; m <= 8; m <<= 1) {
        lp0 += __shfl_xor(lp0, m, 64);
        lp1 += __shfl_xor(lp1, m, 64);
        lp2 += __shfl_xor(lp2, m, 64);
        lp3 += __shfl_xor(lp3, m, 64);
    }
    if (l15 == 0) {
        float4 r;
        r.x = 1.f / lp0; r.y = 1.f / lp1; r.z = 1.f / lp2; r.w = 1.f / lp3;
        *(float4*)(linv + (size_t)b * N_ + key_base + w * 16 + quad * 4) = r;
    }
}

// ---------------------------------------------------------------------------
// Kernel D: out[q,:] = sum_k 2^(alpha*s[q,k]) * (1/l[k]) * V[k,:]
// grid = B * N/64 blocks of 256 (4 waves); block owns 64 q's; loop keys in
// tiles of 64. Phase 1: each wave computes S^T for its 16 keys x 64 q,
// applies exp2 * linv, writes bf16 P to LDS (4 contiguous keys -> b64 write).
// Phase 2: each wave reads PV A-frags for its 16 q's (contiguous b128) and
// accumulates O over 8 d-subtiles with Vt B-frags (contiguous global b128).
// ---------------------------------------------------------------------------
__global__ __launch_bounds__(256) void attn_kernel(
    const __bf16* __restrict__ qb, const __bf16* __restrict__ kb,
    const __bf16* __restrict__ vt, const float* __restrict__ linv,
    float* __restrict__ out)
{
    __shared__ __bf16 plds[64 * 72];   // 64 q-rows x 64 keys, stride 72 (pad 8)

    int b = blockIdx.x >> 6;
    int q_base = (blockIdx.x & 63) * 64;
    int w = threadIdx.x >> 6;
    int L = threadIdx.x & 63;
    int quad = L >> 4, l15 = L & 15;

    const bf16x8* qv = (const bf16x8*)(qb + ((size_t)b * N_) * D_);
    const bf16x8* kv = (const bf16x8*)(kb + ((size_t)b * N_) * D_);
    const bf16x8* vv = (const bf16x8*)(vt + ((size_t)b * D_) * N_);
    const float* lp = linv + (size_t)b * N_;

    // Q^T B-frags for the block's 64 q, resident all kernel
    bf16x8 bq[4][4];
#pragma unroll
    for (int s = 0; s < 4; ++s)
#pragma unroll
        for (int f = 0; f < 4; ++f)
            bq[s][f] = qv[(q_base + s * 16 + l15) * 16 + f * 4 + quad];

    f32x4 oacc[8];
#pragma unroll
    for (int i = 0; i < 8; ++i) oacc[i] = (f32x4){0.f, 0.f, 0.f, 0.f};

    for (int kt = 0; kt < N_; kt += 64) {
        // ---- phase 1: P tile (this wave: keys [kt+16w, kt+16w+16)) ----
        int key0 = kt + w * 16;
        bf16x8 ak[4];
#pragma unroll
        for (int f = 0; f < 4; ++f) ak[f] = kv[(key0 + l15) * 16 + f * 4 + quad];
        float4 il = *(const float4*)(lp + key0 + quad * 4);
#pragma unroll
        for (int s = 0; s < 4; ++s) {
            f32x4 acc = {0.f, 0.f, 0.f, 0.f};
#pragma unroll
            for (int f = 0; f < 4; ++f)
                acc = __builtin_amdgcn_mfma_f32_16x16x32_bf16(ak[f], bq[s][f], acc, 0, 0, 0);
            bf16x4 p;
            p[0] = (__bf16)(__builtin_amdgcn_exp2f(acc[0] * ALPHA) * il.x);
            p[1] = (__bf16)(__builtin_amdgcn_exp2f(acc[1] * ALPHA) * il.y);
            p[2] = (__bf16)(__builtin_amdgcn_exp2f(acc[2] * ALPHA) * il.z);
            p[3] = (__bf16)(__builtin_amdgcn_exp2f(acc[3] * ALPHA) * il.w);
            *(bf16x4*)&plds[(s * 16 + l15) * 72 + w * 16 + quad * 4] = p;
        }
        __syncthreads();
        // ---- phase 2: O += P * V' (this wave: q [q_base+16w, +16)) ----
        bf16x8 ap[2];
#pragma unroll
        for (int kf = 0; kf < 2; ++kf)
            ap[kf] = *(const bf16x8*)&plds[(w * 16 + l15) * 72 + kf * 32 + quad * 8];
#pragma unroll
        for (int dsub = 0; dsub < 8; ++dsub) {
#pragma unroll
            for (int kf = 0; kf < 2; ++kf) {
                bf16x8 bv = vv[((dsub * 16 + l15) * N_ + kt + kf * 32 + quad * 8) / 8];
                oacc[dsub] = __builtin_amdgcn_mfma_f32_16x16x32_bf16(ap[kf], bv, oacc[dsub], 0, 0, 0);
            }
        }
        __syncthreads();
    }

    // epilogue: C-layout rows q = 16w + quad*4 + r, cols d = dsub*16 + l15
    float* op = out + ((size_t)b * N_ + q_base + w * 16) * D_;
#pragma unroll
    for (int dsub = 0; dsub < 8; ++dsub)
#pragma unroll
        for (int r = 0; r < 4; ++r)
            op[(quad * 4 + r) * D_ + dsub * 16 + l15] = oacc[dsub][r];
}

extern "C" void kernel_launch(void* const* d_in, const int* in_sizes, int n_in,
                              void* d_out, int out_size, void* d_ws, size_t ws_size,
                              hipStream_t stream) {
    const float* q = (const float*)d_in[0];
    const float* k = (const float*)d_in[1];
    const float* v = (const float*)d_in[2];
    float* out = (float*)d_out;
    char* ws = (char*)d_ws;
    __bf16* qb = (__bf16*)(ws);
    __bf16* kb = (__bf16*)(ws + (4u << 20));
    __bf16* vt = (__bf16*)(ws + (8u << 20));
    float* linv = (float*)(ws + (12u << 20));

    hipLaunchKernelGGL(cvt_kernel, dim3(6144), dim3(256), 0, stream, q, k, v, qb, kb, vt);
    hipLaunchKernelGGL(stats_kernel, dim3(256), dim3(256), 0, stream, qb, kb, linv);
    hipLaunchKernelGGL(attn_kernel, dim3(256), dim3(256), 0, stream, qb, kb, vt, linv, out);
}

// Round 2
// 372.402 us; speedup vs baseline: 1.1204x; 1.1204x over previous
//
#include <hip/hip_runtime.h>
#include <hip/hip_bf16.h>

#define B_ 4
#define N_ 4096
#define D_ 128
#define KSEG 4
#define QSEG 4

typedef __bf16 bf16x8 __attribute__((ext_vector_type(8)));
typedef __bf16 bf16x4 __attribute__((ext_vector_type(4)));
typedef float f32x4 __attribute__((ext_vector_type(4)));

// alpha = log2(e) / sqrt(128): scores scaled to base-2 domain
#define ALPHA 0.12752361680972262f

// ws layout:
//   Qb   : bf16 [B][N][D]        @ 0       (4 MiB)
//   Kb   : bf16 [B][N][D]        @ 4 MiB
//   Vt   : bf16 [B][D][N]        @ 8 MiB   (transposed V)
//   l    : f32  [B][N]           @ 12 MiB  (column sums, atomic-accumulated)
//   linv : f32  [B][N]           @ 12 MiB + 64 KiB
//   part : f32  [KSEG][B][N][D]  @ 13 MiB  (32 MiB partial outputs)

#define OFF_KB   (4u << 20)
#define OFF_VT   (8u << 20)
#define OFF_L    (12u << 20)
#define OFF_LINV ((12u << 20) + (64u << 10))
#define OFF_PART (13u << 20)

// ---------------------------------------------------------------------------
// Kernel A: convert Q,K -> bf16; convert+transpose V -> Vt
// ---------------------------------------------------------------------------
__global__ __launch_bounds__(256) void cvt_kernel(
    const float* __restrict__ q, const float* __restrict__ k,
    const float* __restrict__ v,
    __bf16* __restrict__ qb, __bf16* __restrict__ kb, __bf16* __restrict__ vt)
{
    int bid = blockIdx.x;
    int tid = threadIdx.x;
    if (bid < 4096) {
        int i4 = bid * 256 + tid;
        const float4* src;
        __bf16* dst;
        int off;
        if (i4 < (B_ * N_ * D_ / 4)) { src = (const float4*)q; dst = qb; off = i4; }
        else { src = (const float4*)k; dst = kb; off = i4 - B_ * N_ * D_ / 4; }
        float4 x = src[off];
        bf16x4 y;
        y[0] = (__bf16)x.x; y[1] = (__bf16)x.y; y[2] = (__bf16)x.z; y[3] = (__bf16)x.w;
        *(bf16x4*)(dst + (size_t)off * 4) = y;
    } else {
        int g = (bid - 4096) * 256 + tid;
        int kg = g & 1023;
        int rest = g >> 10;
        int d = rest & 127;
        int b = rest >> 7;
        const float* vp = v + ((size_t)b * N_ + (size_t)kg * 4) * D_ + d;
        bf16x4 y;
        y[0] = (__bf16)vp[0];
        y[1] = (__bf16)vp[D_];
        y[2] = (__bf16)vp[2 * D_];
        y[3] = (__bf16)vp[3 * D_];
        *(bf16x4*)(vt + ((size_t)b * D_ + d) * N_ + (size_t)kg * 4) = y;
    }
}

// ---------------------------------------------------------------------------
// Kernel B: column stats, q-split. Each block: 64 keys x 1024 q's; partial
// column sums combined via atomicAdd (l zeroed by memset beforehand).
// grid = B * (N/64) * QSEG = 1024 blocks of 256.
// ---------------------------------------------------------------------------
__global__ __launch_bounds__(256) void stats_kernel(
    const __bf16* __restrict__ qb, const __bf16* __restrict__ kb,
    float* __restrict__ l)
{
    int idx = blockIdx.x;
    int qseg = idx & (QSEG - 1);
    int key_base = ((idx >> 2) & 63) * 64;
    int b = idx >> 8;
    int w = threadIdx.x >> 6;
    int L = threadIdx.x & 63;
    int quad = L >> 4, l15 = L & 15;

    const bf16x8* kv = (const bf16x8*)(kb + ((size_t)b * N_) * D_);
    const bf16x8* qv = (const bf16x8*)(qb + ((size_t)b * N_) * D_);

    int arow = key_base + w * 16 + l15;
    bf16x8 af[4];
#pragma unroll
    for (int f = 0; f < 4; ++f) af[f] = kv[arow * 16 + f * 4 + quad];

    float lp0 = 0.f, lp1 = 0.f, lp2 = 0.f, lp3 = 0.f;
    int q0 = qseg * (N_ / QSEG);
    for (int qt = q0; qt < q0 + N_ / QSEG; qt += 64) {
        bf16x8 bq[4][4];
#pragma unroll
        for (int s = 0; s < 4; ++s)
#pragma unroll
            for (int f = 0; f < 4; ++f)
                bq[s][f] = qv[(qt + s * 16 + l15) * 16 + f * 4 + quad];
#pragma unroll
        for (int s = 0; s < 4; ++s) {
            f32x4 acc = {0.f, 0.f, 0.f, 0.f};
#pragma unroll
            for (int f = 0; f < 4; ++f)
                acc = __builtin_amdgcn_mfma_f32_16x16x32_bf16(af[f], bq[s][f], acc, 0, 0, 0);
            lp0 += __builtin_amdgcn_exp2f(acc[0] * ALPHA);
            lp1 += __builtin_amdgcn_exp2f(acc[1] * ALPHA);
            lp2 += __builtin_amdgcn_exp2f(acc[2] * ALPHA);
            lp3 += __builtin_amdgcn_exp2f(acc[3] * ALPHA);
        }
    }
#pragma unroll
    for (int m = 1; m <= 8; m <<= 1) {
        lp0 += __shfl_xor(lp0, m, 64);
        lp1 += __shfl_xor(lp1, m, 64);
        lp2 += __shfl_xor(lp2, m, 64);
        lp3 += __shfl_xor(lp3, m, 64);
    }
    if (l15 == 0) {
        float* dst = l + (size_t)b * N_ + key_base + w * 16 + quad * 4;
        atomicAdd(dst + 0, lp0);
        atomicAdd(dst + 1, lp1);
        atomicAdd(dst + 2, lp2);
        atomicAdd(dst + 3, lp3);
    }
}

// ---------------------------------------------------------------------------
// Kernel C: linv = 1/l  (B*N = 16384 elements)
// ---------------------------------------------------------------------------
__global__ __launch_bounds__(256) void recip_kernel(
    const float* __restrict__ l, float* __restrict__ linv)
{
    int i = blockIdx.x * 256 + threadIdx.x;
    linv[i] = 1.f / l[i];
}

// ---------------------------------------------------------------------------
// Kernel D: key-split attention. grid = B * (N/64) * KSEG = 1024 blocks.
// Each block: 64 q's x 1024 keys -> fp32 partial O into part[seg].
// ---------------------------------------------------------------------------
__global__ __launch_bounds__(256) void attn_kernel(
    const __bf16* __restrict__ qb, const __bf16* __restrict__ kb,
    const __bf16* __restrict__ vt, const float* __restrict__ linv,
    float* __restrict__ part)
{
    __shared__ __bf16 plds[64 * 72];   // 64 q-rows x 64 keys, stride 72 (pad 8)

    int idx = blockIdx.x;
    int seg = idx & (KSEG - 1);
    int q_base = ((idx >> 2) & 63) * 64;
    int b = idx >> 8;
    int w = threadIdx.x >> 6;
    int L = threadIdx.x & 63;
    int quad = L >> 4, l15 = L & 15;

    const bf16x8* qv = (const bf16x8*)(qb + ((size_t)b * N_) * D_);
    const bf16x8* kv = (const bf16x8*)(kb + ((size_t)b * N_) * D_);
    const bf16x8* vv = (const bf16x8*)(vt + ((size_t)b * D_) * N_);
    const float* lp = linv + (size_t)b * N_;

    bf16x8 bq[4][4];
#pragma unroll
    for (int s = 0; s < 4; ++s)
#pragma unroll
        for (int f = 0; f < 4; ++f)
            bq[s][f] = qv[(q_base + s * 16 + l15) * 16 + f * 4 + quad];

    f32x4 oacc[8];
#pragma unroll
    for (int i = 0; i < 8; ++i) oacc[i] = (f32x4){0.f, 0.f, 0.f, 0.f};

    int k0 = seg * (N_ / KSEG);
    for (int kt = k0; kt < k0 + N_ / KSEG; kt += 64) {
        int key0 = kt + w * 16;
        bf16x8 ak[4];
#pragma unroll
        for (int f = 0; f < 4; ++f) ak[f] = kv[(key0 + l15) * 16 + f * 4 + quad];
        float4 il = *(const float4*)(lp + key0 + quad * 4);
#pragma unroll
        for (int s = 0; s < 4; ++s) {
            f32x4 acc = {0.f, 0.f, 0.f, 0.f};
#pragma unroll
            for (int f = 0; f < 4; ++f)
                acc = __builtin_amdgcn_mfma_f32_16x16x32_bf16(ak[f], bq[s][f], acc, 0, 0, 0);
            bf16x4 p;
            p[0] = (__bf16)(__builtin_amdgcn_exp2f(acc[0] * ALPHA) * il.x);
            p[1] = (__bf16)(__builtin_amdgcn_exp2f(acc[1] * ALPHA) * il.y);
            p[2] = (__bf16)(__builtin_amdgcn_exp2f(acc[2] * ALPHA) * il.z);
            p[3] = (__bf16)(__builtin_amdgcn_exp2f(acc[3] * ALPHA) * il.w);
            *(bf16x4*)&plds[(s * 16 + l15) * 72 + w * 16 + quad * 4] = p;
        }
        __syncthreads();
        bf16x8 ap[2];
#pragma unroll
        for (int kf = 0; kf < 2; ++kf)
            ap[kf] = *(const bf16x8*)&plds[(w * 16 + l15) * 72 + kf * 32 + quad * 8];
#pragma unroll
        for (int dsub = 0; dsub < 8; ++dsub) {
#pragma unroll
            for (int kf = 0; kf < 2; ++kf) {
                bf16x8 bv = vv[((dsub * 16 + l15) * N_ + kt + kf * 32 + quad * 8) / 8];
                oacc[dsub] = __builtin_amdgcn_mfma_f32_16x16x32_bf16(ap[kf], bv, oacc[dsub], 0, 0, 0);
            }
        }
        __syncthreads();
    }

    float* op = part + ((size_t)seg * B_ * N_ + (size_t)b * N_ + q_base + w * 16) * D_;
#pragma unroll
    for (int dsub = 0; dsub < 8; ++dsub)
#pragma unroll
        for (int r = 0; r < 4; ++r)
            op[(quad * 4 + r) * D_ + dsub * 16 + l15] = oacc[dsub][r];
}

// ---------------------------------------------------------------------------
// Kernel E: out = sum of KSEG partials. 2M floats, float4 per thread.
// ---------------------------------------------------------------------------
__global__ __launch_bounds__(256) void reduce_kernel(
    const float* __restrict__ part, float* __restrict__ out)
{
    int i = blockIdx.x * 256 + threadIdx.x;      // float4 index
    const f32x4* p = (const f32x4*)part;
    f32x4 s = p[i];
#pragma unroll
    for (int sgi = 1; sgi < KSEG; ++sgi) {
        f32x4 t = p[(size_t)sgi * (B_ * N_ * D_ / 4) + i];
        s[0] += t[0]; s[1] += t[1]; s[2] += t[2]; s[3] += t[3];
    }
    ((f32x4*)out)[i] = s;
}

extern "C" void kernel_launch(void* const* d_in, const int* in_sizes, int n_in,
                              void* d_out, int out_size, void* d_ws, size_t ws_size,
                              hipStream_t stream) {
    const float* q = (const float*)d_in[0];
    const float* k = (const float*)d_in[1];
    const float* v = (const float*)d_in[2];
    float* out = (float*)d_out;
    char* ws = (char*)d_ws;
    __bf16* qb = (__bf16*)(ws);
    __bf16* kb = (__bf16*)(ws + OFF_KB);
    __bf16* vt = (__bf16*)(ws + OFF_VT);
    float* l    = (float*)(ws + OFF_L);
    float* linv = (float*)(ws + OFF_LINV);
    float* part = (float*)(ws + OFF_PART);

    hipLaunchKernelGGL(cvt_kernel, dim3(6144), dim3(256), 0, stream, q, k, v, qb, kb, vt);
    hipMemsetAsync(l, 0, (size_t)B_ * N_ * sizeof(float), stream);
    hipLaunchKernelGGL(stats_kernel, dim3(B_ * (N_ / 64) * QSEG), dim3(256), 0, stream, qb, kb, l);
    hipLaunchKernelGGL(recip_kernel, dim3(B_ * N_ / 256), dim3(256), 0, stream, l, linv);
    hipLaunchKernelGGL(attn_kernel, dim3(B_ * (N_ / 64) * KSEG), dim3(256), 0, stream, qb, kb, vt, linv, part);
    hipLaunchKernelGGL(reduce_kernel, dim3(B_ * N_ * D_ / 4 / 256), dim3(256), 0, stream, part, out);
}

// Round 4
// 176.653 us; speedup vs baseline: 2.3620x; 2.1081x over previous
//
#include <hip/hip_runtime.h>
#include <hip/hip_bf16.h>

#define B_ 4
#define N_ 4096
#define D_ 128
#define KSEG 4
#define QSEG 4
#define NSEG (N_ / KSEG)   // 1024 keys per attn block
#define QSEGN (N_ / QSEG)  // 1024 q's per stats block

typedef __bf16 bf16x8 __attribute__((ext_vector_type(8)));
typedef __bf16 bf16x4 __attribute__((ext_vector_type(4)));
typedef float f32x4 __attribute__((ext_vector_type(4)));

// alpha = log2(e) / sqrt(128): scores in base-2 domain
#define ALPHA 0.12752361680972262f

// ws layout:
//   Qb   : bf16 [B][N][D]        @ 0       (4 MiB)
//   Kb   : bf16 [B][N][D]        @ 4 MiB
//   Vt   : bf16 [B][D][N]        @ 8 MiB
//   l    : f32  [B][N]           @ 12 MiB
//   linv : f32  [B][N]           @ 12 MiB + 64 KiB
//   part : f32  [KSEG][B][N][D]  @ 13 MiB  (32 MiB)
#define OFF_KB   (4u << 20)
#define OFF_VT   (8u << 20)
#define OFF_L    (12u << 20)
#define OFF_LINV ((12u << 20) + (64u << 10))
#define OFF_PART (13u << 20)

// ---------------------------------------------------------------------------
// Kernel A: convert Q,K -> bf16; convert+transpose V -> Vt
// ---------------------------------------------------------------------------
__global__ __launch_bounds__(256) void cvt_kernel(
    const float* __restrict__ q, const float* __restrict__ k,
    const float* __restrict__ v,
    __bf16* __restrict__ qb, __bf16* __restrict__ kb, __bf16* __restrict__ vt)
{
    int bid = blockIdx.x;
    int tid = threadIdx.x;
    if (bid < 4096) {
        int i4 = bid * 256 + tid;
        const float4* src;
        __bf16* dst;
        int off;
        if (i4 < (B_ * N_ * D_ / 4)) { src = (const float4*)q; dst = qb; off = i4; }
        else { src = (const float4*)k; dst = kb; off = i4 - B_ * N_ * D_ / 4; }
        float4 x = src[off];
        bf16x4 y;
        y[0] = (__bf16)x.x; y[1] = (__bf16)x.y; y[2] = (__bf16)x.z; y[3] = (__bf16)x.w;
        *(bf16x4*)(dst + (size_t)off * 4) = y;
    } else {
        int g = (bid - 4096) * 256 + tid;
        int kg = g & 1023;
        int rest = g >> 10;
        int d = rest & 127;
        int b = rest >> 7;
        const float* vp = v + ((size_t)b * N_ + (size_t)kg * 4) * D_ + d;
        bf16x4 y;
        y[0] = (__bf16)vp[0];
        y[1] = (__bf16)vp[D_];
        y[2] = (__bf16)vp[2 * D_];
        y[3] = (__bf16)vp[3 * D_];
        *(bf16x4*)(vt + ((size_t)b * D_ + d) * N_ + (size_t)kg * 4) = y;
    }
}

// ---------------------------------------------------------------------------
// Kernel B: column stats, q-split. Double-buffered LDS Q tile (stride 136,
// pad 8 -> b128 reads at the 8-phase floor), staged via regs + ds_write_b128,
// next tile register-prefetched during compute. One barrier per iteration.
// grid = B * (N/64) * QSEG = 1024 blocks of 256.
// ---------------------------------------------------------------------------
__global__ __launch_bounds__(256) void stats_kernel(
    const __bf16* __restrict__ qb, const __bf16* __restrict__ kb,
    float* __restrict__ l)
{
    __shared__ __bf16 qlds[2][64 * 136];   // 2 x 17 KiB

    int idx = blockIdx.x;
    int qseg = idx & (QSEG - 1);
    int key_base = ((idx >> 2) & 63) * 64;
    int b = idx >> 8;
    int w = threadIdx.x >> 6;
    int L = threadIdx.x & 63;
    int quad = L >> 4, l15 = L & 15;
    int r4 = L >> 4, c16 = L & 15;     // staging lane layout: 4 rows x 16 chunks

    const bf16x8* kv = (const bf16x8*)(kb + (size_t)b * N_ * D_);
    const bf16x8* qv = (const bf16x8*)(qb + (size_t)b * N_ * D_);

    bf16x8 af[4];
#pragma unroll
    for (int f = 0; f < 4; ++f)
        af[f] = kv[(key_base + w * 16 + l15) * 16 + f * 4 + quad];

    int q0 = qseg * QSEGN;
    bf16x8 qr[4];
#pragma unroll
    for (int j = 0; j < 4; ++j)
        qr[j] = qv[(q0 + w * 16 + j * 4 + r4) * 16 + c16];

    float lp0 = 0.f, lp1 = 0.f, lp2 = 0.f, lp3 = 0.f;
    const int T = QSEGN / 64;          // 16
    for (int t = 0; t < T; ++t) {
        int buf = t & 1;
        // commit current tile from regs to LDS
#pragma unroll
        for (int j = 0; j < 4; ++j)
            *(bf16x8*)&qlds[buf][(w * 16 + j * 4 + r4) * 136 + c16 * 8] = qr[j];
        // prefetch next tile (latency hidden under this iteration's MFMA)
        int tn = (t + 1 < T) ? t + 1 : t;
#pragma unroll
        for (int j = 0; j < 4; ++j)
            qr[j] = qv[(q0 + tn * 64 + w * 16 + j * 4 + r4) * 16 + c16];
        __syncthreads();               // qlds[buf] visible to all waves
#pragma unroll
        for (int s = 0; s < 4; ++s) {
            bf16x8 bqf[4];
#pragma unroll
            for (int f = 0; f < 4; ++f)
                bqf[f] = *(const bf16x8*)&qlds[buf][(s * 16 + l15) * 136 + (f * 4 + quad) * 8];
            f32x4 acc = {0.f, 0.f, 0.f, 0.f};
#pragma unroll
            for (int f = 0; f < 4; ++f)
                acc = __builtin_amdgcn_mfma_f32_16x16x32_bf16(af[f], bqf[f], acc, 0, 0, 0);
            lp0 += __builtin_amdgcn_exp2f(acc[0] * ALPHA);
            lp1 += __builtin_amdgcn_exp2f(acc[1] * ALPHA);
            lp2 += __builtin_amdgcn_exp2f(acc[2] * ALPHA);
            lp3 += __builtin_amdgcn_exp2f(acc[3] * ALPHA);
        }
    }
#pragma unroll
    for (int m = 1; m <= 8; m <<= 1) {
        lp0 += __shfl_xor(lp0, m, 64);
        lp1 += __shfl_xor(lp1, m, 64);
        lp2 += __shfl_xor(lp2, m, 64);
        lp3 += __shfl_xor(lp3, m, 64);
    }
    if (l15 == 0) {
        float* dst = l + (size_t)b * N_ + key_base + w * 16 + quad * 4;
        atomicAdd(dst + 0, lp0);
        atomicAdd(dst + 1, lp1);
        atomicAdd(dst + 2, lp2);
        atomicAdd(dst + 3, lp3);
    }
}

// ---------------------------------------------------------------------------
// Kernel C: linv = 1/l
// ---------------------------------------------------------------------------
__global__ __launch_bounds__(256) void recip_kernel(
    const float* __restrict__ l, float* __restrict__ linv)
{
    int i = blockIdx.x * 256 + threadIdx.x;
    linv[i] = 1.f / l[i];
}

// ---------------------------------------------------------------------------
// Kernel D: key-split attention. Vt tile staged via regs + ds_write_b128 into
// padded vlds (stride 72 -> reads/writes at the 8-phase floor); next tile's
// Vt and K frags register-prefetched at iteration top. P tile via the
// R2-proven stride-72 plds round trip. 2 barriers/iter.
// grid = B * (N/64) * KSEG = 1024 blocks of 256.
// ---------------------------------------------------------------------------
__global__ __launch_bounds__(256) void attn_kernel(
    const __bf16* __restrict__ qb, const __bf16* __restrict__ kb,
    const __bf16* __restrict__ vt, const float* __restrict__ linv,
    float* __restrict__ part)
{
    __shared__ __bf16 plds[64 * 72];     // 9 KiB
    __shared__ __bf16 vlds[128 * 72];    // 18 KiB

    int idx = blockIdx.x;
    int seg = idx & (KSEG - 1);
    int q_base = ((idx >> 2) & 63) * 64;
    int b = idx >> 8;
    int w = threadIdx.x >> 6;
    int L = threadIdx.x & 63;
    int quad = L >> 4, l15 = L & 15;
    int r8 = L >> 3, c8 = L & 7;        // Vt staging: 8 rows x 8 chunks per instr

    const bf16x8* qv = (const bf16x8*)(qb + (size_t)b * N_ * D_);
    const bf16x8* kv = (const bf16x8*)(kb + (size_t)b * N_ * D_);
    const bf16x8* vv = (const bf16x8*)(vt + (size_t)b * D_ * N_);
    const float* lp = linv + (size_t)b * N_;

    bf16x8 bq[4][4];
#pragma unroll
    for (int s = 0; s < 4; ++s)
#pragma unroll
        for (int f = 0; f < 4; ++f)
            bq[s][f] = qv[(q_base + s * 16 + l15) * 16 + f * 4 + quad];

    f32x4 oacc[8];
#pragma unroll
    for (int i = 0; i < 8; ++i) oacc[i] = (f32x4){0.f, 0.f, 0.f, 0.f};

    int k0 = seg * NSEG;
    const int T = NSEG / 64;            // 16

    bf16x8 ak[4], akn[4], vtr[4];
#pragma unroll
    for (int f = 0; f < 4; ++f)
        ak[f] = kv[(k0 + w * 16 + l15) * 16 + f * 4 + quad];
#pragma unroll
    for (int j = 0; j < 4; ++j)
        vtr[j] = vv[(size_t)(w * 32 + j * 8 + r8) * (N_ / 8) + k0 / 8 + c8];

    for (int t = 0; t < T; ++t) {
        int kt = k0 + t * 64;
        // commit current Vt tile to LDS (reads of previous tile ended at the
        // end-of-iteration barrier)
#pragma unroll
        for (int j = 0; j < 4; ++j)
            *(bf16x8*)&vlds[(w * 32 + j * 8 + r8) * 72 + c8 * 8] = vtr[j];
        // prefetch next tile's K frags and Vt rows
        int ktn = (t + 1 < T) ? kt + 64 : kt;
#pragma unroll
        for (int f = 0; f < 4; ++f)
            akn[f] = kv[(ktn + w * 16 + l15) * 16 + f * 4 + quad];
#pragma unroll
        for (int j = 0; j < 4; ++j)
            vtr[j] = vv[(size_t)(w * 32 + j * 8 + r8) * (N_ / 8) + ktn / 8 + c8];

        // phase 1: S^T -> P (this wave: keys [kt+16w, +16))
        float4 il = *(const float4*)(lp + kt + w * 16 + quad * 4);
#pragma unroll
        for (int s = 0; s < 4; ++s) {
            f32x4 acc = {0.f, 0.f, 0.f, 0.f};
#pragma unroll
            for (int f = 0; f < 4; ++f)
                acc = __builtin_amdgcn_mfma_f32_16x16x32_bf16(ak[f], bq[s][f], acc, 0, 0, 0);
            bf16x4 p;
            p[0] = (__bf16)(__builtin_amdgcn_exp2f(acc[0] * ALPHA) * il.x);
            p[1] = (__bf16)(__builtin_amdgcn_exp2f(acc[1] * ALPHA) * il.y);
            p[2] = (__bf16)(__builtin_amdgcn_exp2f(acc[2] * ALPHA) * il.z);
            p[3] = (__bf16)(__builtin_amdgcn_exp2f(acc[3] * ALPHA) * il.w);
            *(bf16x4*)&plds[(s * 16 + l15) * 72 + w * 16 + quad * 4] = p;
        }
        __syncthreads();   // plds + vlds writes visible

        // phase 2: O += P * Vt (this wave: q [q_base+16w, +16))
        bf16x8 ap[2];
#pragma unroll
        for (int kf = 0; kf < 2; ++kf)
            ap[kf] = *(const bf16x8*)&plds[(w * 16 + l15) * 72 + kf * 32 + quad * 8];
#pragma unroll
        for (int dsub = 0; dsub < 8; ++dsub) {
#pragma unroll
            for (int kf = 0; kf < 2; ++kf) {
                bf16x8 bv = *(const bf16x8*)&vlds[(dsub * 16 + l15) * 72 + (kf * 4 + quad) * 8];
                oacc[dsub] = __builtin_amdgcn_mfma_f32_16x16x32_bf16(ap[kf], bv, oacc[dsub], 0, 0, 0);
            }
        }
        __syncthreads();   // protect plds/vlds for next iteration
#pragma unroll
        for (int f = 0; f < 4; ++f) ak[f] = akn[f];
    }

    float* op = part + ((size_t)seg * B_ * N_ + (size_t)b * N_ + q_base + w * 16) * D_;
#pragma unroll
    for (int dsub = 0; dsub < 8; ++dsub)
#pragma unroll
        for (int r = 0; r < 4; ++r)
            op[(quad * 4 + r) * D_ + dsub * 16 + l15] = oacc[dsub][r];
}

// ---------------------------------------------------------------------------
// Kernel E: out = sum of KSEG partials
// ---------------------------------------------------------------------------
__global__ __launch_bounds__(256) void reduce_kernel(
    const float* __restrict__ part, float* __restrict__ out)
{
    int i = blockIdx.x * 256 + threadIdx.x;
    const f32x4* p = (const f32x4*)part;
    f32x4 s = p[i];
#pragma unroll
    for (int sgi = 1; sgi < KSEG; ++sgi) {
        f32x4 t = p[(size_t)sgi * (B_ * N_ * D_ / 4) + i];
        s[0] += t[0]; s[1] += t[1]; s[2] += t[2]; s[3] += t[3];
    }
    ((f32x4*)out)[i] = s;
}

extern "C" void kernel_launch(void* const* d_in, const int* in_sizes, int n_in,
                              void* d_out, int out_size, void* d_ws, size_t ws_size,
                              hipStream_t stream) {
    const float* q = (const float*)d_in[0];
    const float* k = (const float*)d_in[1];
    const float* v = (const float*)d_in[2];
    float* out = (float*)d_out;
    char* ws = (char*)d_ws;
    __bf16* qb = (__bf16*)(ws);
    __bf16* kb = (__bf16*)(ws + OFF_KB);
    __bf16* vt = (__bf16*)(ws + OFF_VT);
    float* l    = (float*)(ws + OFF_L);
    float* linv = (float*)(ws + OFF_LINV);
    float* part = (float*)(ws + OFF_PART);

    hipLaunchKernelGGL(cvt_kernel, dim3(6144), dim3(256), 0, stream, q, k, v, qb, kb, vt);
    hipMemsetAsync(l, 0, (size_t)B_ * N_ * sizeof(float), stream);
    hipLaunchKernelGGL(stats_kernel, dim3(B_ * (N_ / 64) * QSEG), dim3(256), 0, stream, qb, kb, l);
    hipLaunchKernelGGL(recip_kernel, dim3(B_ * N_ / 256), dim3(256), 0, stream, l, linv);
    hipLaunchKernelGGL(attn_kernel, dim3(B_ * (N_ / 64) * KSEG), dim3(256), 0, stream, qb, kb, vt, linv, part);
    hipLaunchKernelGGL(reduce_kernel, dim3(B_ * N_ * D_ / 4 / 256), dim3(256), 0, stream, part, out);
}

// Round 5
// 168.605 us; speedup vs baseline: 2.4747x; 1.0477x over previous
//
#include <hip/hip_runtime.h>
#include <hip/hip_bf16.h>

#define B_ 4
#define N_ 4096
#define D_ 128
#define KSEG 4
#define QSEG 4
#define NSEG (N_ / KSEG)   // 1024 keys per attn block
#define QSEGN (N_ / QSEG)  // 1024 q's per stats block

typedef __bf16 bf16x8 __attribute__((ext_vector_type(8)));
typedef __bf16 bf16x4 __attribute__((ext_vector_type(4)));
typedef float f32x4 __attribute__((ext_vector_type(4)));

// alpha = log2(e) / sqrt(128), folded into Qb at conversion time
#define ALPHA 0.12752361680972262f

// ws layout:
//   Qb   : bf16 [B][N][D]        @ 0       (alpha-prescaled)
//   Kb   : bf16 [B][N][D]        @ 4 MiB
//   Vt   : bf16 [B][D][N]        @ 8 MiB   (transposed V; linv-scaled in place)
//   l    : f32  [B][N]           @ 12 MiB
//   linv : f32  [B][N]           @ 12 MiB + 64 KiB
//   part : f32  [KSEG][B][N][D]  @ 13 MiB  (32 MiB)
#define OFF_KB   (4u << 20)
#define OFF_VT   (8u << 20)
#define OFF_L    (12u << 20)
#define OFF_LINV ((12u << 20) + (64u << 10))
#define OFF_PART (13u << 20)

// ---------------------------------------------------------------------------
// Kernel A: convert Q*alpha,K -> bf16; convert+transpose V -> Vt
// ---------------------------------------------------------------------------
__global__ __launch_bounds__(256) void cvt_kernel(
    const float* __restrict__ q, const float* __restrict__ k,
    const float* __restrict__ v,
    __bf16* __restrict__ qb, __bf16* __restrict__ kb, __bf16* __restrict__ vt)
{
    int bid = blockIdx.x;
    int tid = threadIdx.x;
    if (bid < 4096) {
        int i4 = bid * 256 + tid;
        const float4* src;
        __bf16* dst;
        int off;
        float sc;
        if (i4 < (B_ * N_ * D_ / 4)) { src = (const float4*)q; dst = qb; off = i4; sc = ALPHA; }
        else { src = (const float4*)k; dst = kb; off = i4 - B_ * N_ * D_ / 4; sc = 1.f; }
        float4 x = src[off];
        bf16x4 y;
        y[0] = (__bf16)(x.x * sc); y[1] = (__bf16)(x.y * sc);
        y[2] = (__bf16)(x.z * sc); y[3] = (__bf16)(x.w * sc);
        *(bf16x4*)(dst + (size_t)off * 4) = y;
    } else {
        int g = (bid - 4096) * 256 + tid;
        int kg = g & 1023;
        int rest = g >> 10;
        int d = rest & 127;
        int b = rest >> 7;
        const float* vp = v + ((size_t)b * N_ + (size_t)kg * 4) * D_ + d;
        bf16x4 y;
        y[0] = (__bf16)vp[0];
        y[1] = (__bf16)vp[D_];
        y[2] = (__bf16)vp[2 * D_];
        y[3] = (__bf16)vp[3 * D_];
        *(bf16x4*)(vt + ((size_t)b * D_ + d) * N_ + (size_t)kg * 4) = y;
    }
}

// ---------------------------------------------------------------------------
// Kernel B: column stats, q-split. Wave w = (key-half kh, q-half qh): owns
// 32 keys x 32 q of the 64x64 S-tile -> each wave reads only half the Q tile
// from LDS (8 b128/iter vs 16). Double-buffered qlds (stride 136), reg-staged.
// grid = B * (N/64) * QSEG = 1024 blocks of 256.
// ---------------------------------------------------------------------------
__global__ __launch_bounds__(256) void stats_kernel(
    const __bf16* __restrict__ qb, const __bf16* __restrict__ kb,
    float* __restrict__ l)
{
    __shared__ __bf16 qlds[2][64 * 136];   // 2 x 17 KiB

    int idx = blockIdx.x;
    int qseg = idx & (QSEG - 1);
    int key_base = ((idx >> 2) & 63) * 64;
    int b = idx >> 8;
    int w = threadIdx.x >> 6;
    int L = threadIdx.x & 63;
    int quad = L >> 4, l15 = L & 15;
    int r4 = L >> 4, c16 = L & 15;     // staging lane layout: 4 rows x 16 chunks
    int kh = w & 1, qh = w >> 1;

    const bf16x8* kv = (const bf16x8*)(kb + (size_t)b * N_ * D_);
    const bf16x8* qv = (const bf16x8*)(qb + (size_t)b * N_ * D_);

    // A-frags for this wave's 32 keys (2 x 16-key subtiles)
    bf16x8 af[2][4];
#pragma unroll
    for (int i = 0; i < 2; ++i)
#pragma unroll
        for (int f = 0; f < 4; ++f)
            af[i][f] = kv[(key_base + kh * 32 + i * 16 + l15) * 16 + f * 4 + quad];

    int q0 = qseg * QSEGN;
    bf16x8 qr[4];
#pragma unroll
    for (int j = 0; j < 4; ++j)
        qr[j] = qv[(q0 + w * 16 + j * 4 + r4) * 16 + c16];

    float ps[8];                       // per-key partials: slot = i*4 + r
#pragma unroll
    for (int s = 0; s < 8; ++s) ps[s] = 0.f;

    const int T = QSEGN / 64;          // 16
    for (int t = 0; t < T; ++t) {
        int buf = t & 1;
#pragma unroll
        for (int j = 0; j < 4; ++j)
            *(bf16x8*)&qlds[buf][(w * 16 + j * 4 + r4) * 136 + c16 * 8] = qr[j];
        int tn = (t + 1 < T) ? t + 1 : t;
#pragma unroll
        for (int j = 0; j < 4; ++j)
            qr[j] = qv[(q0 + tn * 64 + w * 16 + j * 4 + r4) * 16 + c16];
        __syncthreads();
#pragma unroll
        for (int j2 = 0; j2 < 2; ++j2) {
            bf16x8 bqf[4];
#pragma unroll
            for (int f = 0; f < 4; ++f)
                bqf[f] = *(const bf16x8*)&qlds[buf][(qh * 32 + j2 * 16 + l15) * 136 +
                                                    (f * 4 + quad) * 8];
#pragma unroll
            for (int i = 0; i < 2; ++i) {
                f32x4 acc = {0.f, 0.f, 0.f, 0.f};
#pragma unroll
                for (int f = 0; f < 4; ++f)
                    acc = __builtin_amdgcn_mfma_f32_16x16x32_bf16(af[i][f], bqf[f], acc, 0, 0, 0);
#pragma unroll
                for (int r = 0; r < 4; ++r)
                    ps[i * 4 + r] += __builtin_amdgcn_exp2f(acc[r]);
            }
        }
    }
    // reduce over the 16 q-columns (lanes sharing a quad)
#pragma unroll
    for (int m = 1; m <= 8; m <<= 1)
#pragma unroll
        for (int s = 0; s < 8; ++s)
            ps[s] += __shfl_xor(ps[s], m, 64);
    if (l15 == 0) {
        // keys: key_base + kh*32 + i*16 + quad*4 + r
        float* dst = l + (size_t)b * N_ + key_base + kh * 32 + quad * 4;
#pragma unroll
        for (int i = 0; i < 2; ++i)
#pragma unroll
            for (int r = 0; r < 4; ++r)
                atomicAdd(dst + i * 16 + r, ps[i * 4 + r]);
    }
}

// ---------------------------------------------------------------------------
// Kernel C: linv = 1/l
// ---------------------------------------------------------------------------
__global__ __launch_bounds__(256) void recip_kernel(
    const float* __restrict__ l, float* __restrict__ linv)
{
    int i = blockIdx.x * 256 + threadIdx.x;
    linv[i] = 1.f / l[i];
}

// ---------------------------------------------------------------------------
// Kernel C2: Vt[b][d][k] *= linv[b][k]  (folds normalization into V)
// 262144 bf16x8 chunks, 1024 blocks of 256.
// ---------------------------------------------------------------------------
__global__ __launch_bounds__(256) void scalev_kernel(
    const float* __restrict__ linv, __bf16* __restrict__ vt)
{
    int i = blockIdx.x * 256 + threadIdx.x;  // bf16x8 chunk index
    int row = i >> 9;                        // (b,d) row; N_/8 = 512 chunks/row
    int b = row >> 7;
    int k0 = (i & 511) * 8;
    const float* lp = linv + (size_t)b * N_ + k0;
    float4 a = *(const float4*)lp;
    float4 c = *(const float4*)(lp + 4);
    bf16x8 v = ((const bf16x8*)vt)[i];
    bf16x8 o;
    o[0] = (__bf16)((float)v[0] * a.x); o[1] = (__bf16)((float)v[1] * a.y);
    o[2] = (__bf16)((float)v[2] * a.z); o[3] = (__bf16)((float)v[3] * a.w);
    o[4] = (__bf16)((float)v[4] * c.x); o[5] = (__bf16)((float)v[5] * c.y);
    o[6] = (__bf16)((float)v[6] * c.z); o[7] = (__bf16)((float)v[7] * c.w);
    ((bf16x8*)vt)[i] = o;
}

// ---------------------------------------------------------------------------
// Kernel D: key-split attention. Phase 1 as R4 (wave = 16 keys x 64 q, E only:
// alpha pre-folded into Qb, linv pre-folded into Vt). Phase 2 reassigned:
// wave (qh = w&1, dh = w>>1) owns 32 q x 64 d -> reads only half of V tile
// (12 b128/iter vs 18). All fragment layouts identical to the R4-proven ones.
// grid = B * (N/64) * KSEG = 1024 blocks of 256.
// ---------------------------------------------------------------------------
__global__ __launch_bounds__(256) void attn_kernel(
    const __bf16* __restrict__ qb, const __bf16* __restrict__ kb,
    const __bf16* __restrict__ vt, float* __restrict__ part)
{
    __shared__ __bf16 plds[64 * 72];     // 9 KiB
    __shared__ __bf16 vlds[128 * 72];    // 18 KiB

    int idx = blockIdx.x;
    int seg = idx & (KSEG - 1);
    int q_base = ((idx >> 2) & 63) * 64;
    int b = idx >> 8;
    int w = threadIdx.x >> 6;
    int L = threadIdx.x & 63;
    int quad = L >> 4, l15 = L & 15;
    int r8 = L >> 3, c8 = L & 7;        // Vt staging: 8 rows x 8 chunks per instr
    int qh = w & 1, dh = w >> 1;

    const bf16x8* qv = (const bf16x8*)(qb + (size_t)b * N_ * D_);
    const bf16x8* kv = (const bf16x8*)(kb + (size_t)b * N_ * D_);
    const bf16x8* vv = (const bf16x8*)(vt + (size_t)b * D_ * N_);

    bf16x8 bq[4][4];
#pragma unroll
    for (int s = 0; s < 4; ++s)
#pragma unroll
        for (int f = 0; f < 4; ++f)
            bq[s][f] = qv[(q_base + s * 16 + l15) * 16 + f * 4 + quad];

    f32x4 oacc[2][4];
#pragma unroll
    for (int s2 = 0; s2 < 2; ++s2)
#pragma unroll
        for (int d2 = 0; d2 < 4; ++d2) oacc[s2][d2] = (f32x4){0.f, 0.f, 0.f, 0.f};

    int k0 = seg * NSEG;
    const int T = NSEG / 64;            // 16

    bf16x8 ak[4], akn[4], vtr[4];
#pragma unroll
    for (int f = 0; f < 4; ++f)
        ak[f] = kv[(k0 + w * 16 + l15) * 16 + f * 4 + quad];
#pragma unroll
    for (int j = 0; j < 4; ++j)
        vtr[j] = vv[(size_t)(w * 32 + j * 8 + r8) * (N_ / 8) + k0 / 8 + c8];

    for (int t = 0; t < T; ++t) {
        int kt = k0 + t * 64;
        // commit current Vt tile to LDS
#pragma unroll
        for (int j = 0; j < 4; ++j)
            *(bf16x8*)&vlds[(w * 32 + j * 8 + r8) * 72 + c8 * 8] = vtr[j];
        // prefetch next tile's K frags and Vt rows
        int ktn = (t + 1 < T) ? kt + 64 : kt;
#pragma unroll
        for (int f = 0; f < 4; ++f)
            akn[f] = kv[(ktn + w * 16 + l15) * 16 + f * 4 + quad];
#pragma unroll
        for (int j = 0; j < 4; ++j)
            vtr[j] = vv[(size_t)(w * 32 + j * 8 + r8) * (N_ / 8) + ktn / 8 + c8];

        // phase 1: E^T tile (this wave: keys [kt+16w, +16) x 64 q)
#pragma unroll
        for (int s = 0; s < 4; ++s) {
            f32x4 acc = {0.f, 0.f, 0.f, 0.f};
#pragma unroll
            for (int f = 0; f < 4; ++f)
                acc = __builtin_amdgcn_mfma_f32_16x16x32_bf16(ak[f], bq[s][f], acc, 0, 0, 0);
            bf16x4 p;
            p[0] = (__bf16)__builtin_amdgcn_exp2f(acc[0]);
            p[1] = (__bf16)__builtin_amdgcn_exp2f(acc[1]);
            p[2] = (__bf16)__builtin_amdgcn_exp2f(acc[2]);
            p[3] = (__bf16)__builtin_amdgcn_exp2f(acc[3]);
            *(bf16x4*)&plds[(s * 16 + l15) * 72 + w * 16 + quad * 4] = p;
        }
        __syncthreads();   // plds + vlds writes visible

        // phase 2: O += P * Vt (this wave: q [q_base+32qh, +32) x d [64dh, +64))
        bf16x8 ap[2][2];
#pragma unroll
        for (int s2 = 0; s2 < 2; ++s2)
#pragma unroll
            for (int kf = 0; kf < 2; ++kf)
                ap[s2][kf] = *(const bf16x8*)&plds[(qh * 32 + s2 * 16 + l15) * 72 +
                                                   kf * 32 + quad * 8];
#pragma unroll
        for (int d2 = 0; d2 < 4; ++d2) {
#pragma unroll
            for (int kf = 0; kf < 2; ++kf) {
                bf16x8 bv = *(const bf16x8*)&vlds[(dh * 64 + d2 * 16 + l15) * 72 +
                                                  (kf * 4 + quad) * 8];
#pragma unroll
                for (int s2 = 0; s2 < 2; ++s2)
                    oacc[s2][d2] = __builtin_amdgcn_mfma_f32_16x16x32_bf16(
                        ap[s2][kf], bv, oacc[s2][d2], 0, 0, 0);
            }
        }
        __syncthreads();   // protect plds/vlds for next iteration
#pragma unroll
        for (int f = 0; f < 4; ++f) ak[f] = akn[f];
    }

    // epilogue: q = q_base + qh*32 + s2*16 + quad*4 + r ; d = dh*64 + d2*16 + l15
    float* op = part + ((size_t)seg * B_ * N_ + (size_t)b * N_ + q_base + qh * 32) * D_ + dh * 64;
#pragma unroll
    for (int s2 = 0; s2 < 2; ++s2)
#pragma unroll
        for (int d2 = 0; d2 < 4; ++d2)
#pragma unroll
            for (int r = 0; r < 4; ++r)
                op[(s2 * 16 + quad * 4 + r) * D_ + d2 * 16 + l15] = oacc[s2][d2][r];
}

// ---------------------------------------------------------------------------
// Kernel E: out = sum of KSEG partials
// ---------------------------------------------------------------------------
__global__ __launch_bounds__(256) void reduce_kernel(
    const float* __restrict__ part, float* __restrict__ out)
{
    int i = blockIdx.x * 256 + threadIdx.x;
    const f32x4* p = (const f32x4*)part;
    f32x4 s = p[i];
#pragma unroll
    for (int sgi = 1; sgi < KSEG; ++sgi) {
        f32x4 t = p[(size_t)sgi * (B_ * N_ * D_ / 4) + i];
        s[0] += t[0]; s[1] += t[1]; s[2] += t[2]; s[3] += t[3];
    }
    ((f32x4*)out)[i] = s;
}

extern "C" void kernel_launch(void* const* d_in, const int* in_sizes, int n_in,
                              void* d_out, int out_size, void* d_ws, size_t ws_size,
                              hipStream_t stream) {
    const float* q = (const float*)d_in[0];
    const float* k = (const float*)d_in[1];
    const float* v = (const float*)d_in[2];
    float* out = (float*)d_out;
    char* ws = (char*)d_ws;
    __bf16* qb = (__bf16*)(ws);
    __bf16* kb = (__bf16*)(ws + OFF_KB);
    __bf16* vt = (__bf16*)(ws + OFF_VT);
    float* l    = (float*)(ws + OFF_L);
    float* linv = (float*)(ws + OFF_LINV);
    float* part = (float*)(ws + OFF_PART);

    hipLaunchKernelGGL(cvt_kernel, dim3(6144), dim3(256), 0, stream, q, k, v, qb, kb, vt);
    hipMemsetAsync(l, 0, (size_t)B_ * N_ * sizeof(float), stream);
    hipLaunchKernelGGL(stats_kernel, dim3(B_ * (N_ / 64) * QSEG), dim3(256), 0, stream, qb, kb, l);
    hipLaunchKernelGGL(recip_kernel, dim3(B_ * N_ / 256), dim3(256), 0, stream, l, linv);
    hipLaunchKernelGGL(scalev_kernel, dim3(B_ * D_ * N_ / 8 / 256), dim3(256), 0, stream, linv, vt);
    hipLaunchKernelGGL(attn_kernel, dim3(B_ * (N_ / 64) * KSEG), dim3(256), 0, stream, qb, kb, vt, part);
    hipLaunchKernelGGL(reduce_kernel, dim3(B_ * N_ * D_ / 4 / 256), dim3(256), 0, stream, part, out);
}